// Round 1
// 345.408 us; speedup vs baseline: 1.0164x; 1.0164x over previous
//
#include <hip/hip_runtime.h>

// Fused BN(affine)+ReLU -> 2x2 AvgPool -> 1x1 Conv (channel GEMM 32->16).
// x: [32, 32, 256, 256] fp32, w: [32, 16] fp32, scale/bias: [32] fp32
// out: [32, 16, 128, 128] fp32
//
// Memory-bound: 268 MB in + 33.5 MB out => ~48 us floor at 6.3 TB/s.
//
// R4 (this round): 4 output px per thread (one w-quad = 8 input floats/row).
//  - Stores: 16 x f32x4 (16 B/lane); a wave covers two full adjacent output
//    rows = 1024 B contiguous per store instr. Store instr count halves.
//  - Loads: 4 x dwordx4 per channel; the (p, p+4) pair are complementary
//    halves of the same 64B lines, issued back-to-back -> full line use.
//  - 131072 threads = 512 blocks x 256 = 8 waves/CU; unroll 4 keeps
//    16 x 1KB wave-loads in flight (128 KB/CU >> 10 KB BW*latency product).
// Weights/scale/bias remain wave-uniform scalar (s_load) operands; no LDS.

#define C_IN  32
#define C_OUT 16
#define H_IN  256
#define W_IN  256
#define H_OUT 128
#define W_OUT 128

typedef float f32x4 __attribute__((ext_vector_type(4)));

__global__ __launch_bounds__(256) void fused_bn_relu_pool_conv(
    const float* __restrict__ x,
    const float* __restrict__ w,      // [C_IN][C_OUT]
    const float* __restrict__ scale,  // [C_IN]
    const float* __restrict__ bias,   // [C_IN]
    float* __restrict__ out)
{
    // Global index: wq in [0,32) (4 out px), h in [0,128), n in [0,32)
    const int gid = blockIdx.x * 256 + threadIdx.x;
    const int wq = gid & 31;
    const int h  = (gid >> 5) & 127;
    const int n  = gid >> 12;

    const float* xbase = x + ((size_t)(n * C_IN) * H_IN + 2 * h) * W_IN + 8 * wq;

    f32x4 acc[C_OUT];
    #pragma unroll
    for (int d = 0; d < C_OUT; ++d) acc[d] = (f32x4)0.f;

    #pragma unroll 4
    for (int c = 0; c < C_IN; ++c) {
        const float* p = xbase + c * (H_IN * W_IN);
        const f32x4 r0a = __builtin_nontemporal_load(reinterpret_cast<const f32x4*>(p));
        const f32x4 r0b = __builtin_nontemporal_load(reinterpret_cast<const f32x4*>(p + 4));
        const f32x4 r1a = __builtin_nontemporal_load(reinterpret_cast<const f32x4*>(p + W_IN));
        const f32x4 r1b = __builtin_nontemporal_load(reinterpret_cast<const f32x4*>(p + W_IN + 4));

        // Wave-uniform -> scalar loads into SGPRs (no LDS, no VGPR cost)
        const float s = scale[c];
        const float b = bias[c];

        // BN + ReLU, packed (v_pk_fma_f32 + v_pk_max_f32)
        f32x4 t0a = r0a * s + b;
        f32x4 t0b = r0b * s + b;
        f32x4 t1a = r1a * s + b;
        f32x4 t1b = r1b * s + b;
        t0a = __builtin_elementwise_max(t0a, (f32x4)0.f);
        t0b = __builtin_elementwise_max(t0b, (f32x4)0.f);
        t1a = __builtin_elementwise_max(t1a, (f32x4)0.f);
        t1b = __builtin_elementwise_max(t1b, (f32x4)0.f);

        // 2x2 pool: vertical pk_add, horizontal scalar adds, 0.25 as pk_mul
        const f32x4 ta = t0a + t1a;
        const f32x4 tb = t0b + t1b;
        f32x4 pp;
        pp.x = ta.x + ta.y;
        pp.y = ta.z + ta.w;
        pp.z = tb.x + tb.y;
        pp.w = tb.z + tb.w;
        pp *= 0.25f;

        // Channel GEMM: 16 x (2 v_pk_fma_f32), weight operand from SGPR
        #pragma unroll
        for (int d = 0; d < C_OUT; ++d) {
            acc[d] += pp * w[c * C_OUT + d];
        }
    }

    // Lanes 0-31 cover full out row h, lanes 32-63 row h+1:
    // one store instr = 1024 B contiguous.
    float* obase = out + ((size_t)(n * C_OUT) * H_OUT + h) * W_OUT + 4 * wq;
    #pragma unroll
    for (int d = 0; d < C_OUT; ++d) {
        __builtin_nontemporal_store(acc[d], reinterpret_cast<f32x4*>(obase + (size_t)d * (H_OUT * W_OUT)));
    }
}

extern "C" void kernel_launch(void* const* d_in, const int* in_sizes, int n_in,
                              void* d_out, int out_size, void* d_ws, size_t ws_size,
                              hipStream_t stream) {
    const float* x     = (const float*)d_in[0];
    const float* w     = (const float*)d_in[1];
    const float* scale = (const float*)d_in[2];
    const float* bias  = (const float*)d_in[3];
    float* out = (float*)d_out;

    // 32 n * 128 h * 32 w-quads = 131072 threads = 512 blocks of 256
    const int total = 32 * H_OUT * (W_OUT / 4);
    fused_bn_relu_pool_conv<<<total / 256, 256, 0, stream>>>(x, w, scale, bias, out);
}